// Round 2
// baseline (1738.613 us; speedup 1.0000x reference)
//
#include <hip/hip_runtime.h>
#include <math.h>

#define B_ 1024
#define V_ 5000
#define N_ 10000
#define T_ 50
#define H_ 200
#define K_ 20
#define EPS_ 1e-5f
#define NSLAB 25
#define PROWS_ 10048   // 157*64, padded row count for P slabs
#define KSPLIT 5

__device__ __forceinline__ float sp_(float x) {
    return (x > 20.f) ? x : log1pf(expf(x));
}

// ---------------- init: zero buckets + cnt, compute tbn[n] = ||theta_bank[n]||^2 ----------------
__global__ __launch_bounds__(256) void k_init(const float* __restrict__ tb,
                                              float* __restrict__ tbn,
                                              float* buckets, int* cnt) {
    int i = blockIdx.x * 256 + threadIdx.x;
    if (blockIdx.x == 0) {
        int t = threadIdx.x;
#pragma unroll
        for (int s = 0; s < 4; ++s) buckets[t + 256 * s] = 0.f;
        if (t < 64) cnt[t] = 0;
    }
    if (i < N_) {
        const float* r = tb + (size_t)i * T_;
        float s = 0.f;
#pragma unroll
        for (int t = 0; t < T_; ++t) { float x = r[t]; s += x * x; }
        tbn[i] = s;
    }
}

// fallback-only: zero e1a when using the atomic path
__global__ __launch_bounds__(256) void k_zero(float* p) {
    int i = blockIdx.x * 256 + threadIdx.x;
    if (i < B_ * H_) p[i] = 0.f;
}

// ---------------- GEMM1: e1 partials = inputs @ W11^T  (k-split, 25 slabs or atomics) ----------------
// grid (16, 25): 64-row tile x full 200 cols, K-chunk = 200
template <bool ATOMIC>
__global__ __launch_bounds__(256) void k_gemm1(const float* __restrict__ X,
                                               const float* __restrict__ W,
                                               float* __restrict__ e1p) {
    __shared__ __align__(16) float Al[64][12];   // stride 12: 4-way LDS conflict instead of 8-way
    __shared__ __align__(16) float Bl[200][8];
    const int tid = threadIdx.x;
    const int r = tid & 31, c = tid >> 5;       // r: row pair, c: 0..7 col group of 25
    const int m0 = blockIdx.x * 64;
    const int k0 = blockIdx.y * 200;
    float acc0[25], acc1[25];
#pragma unroll
    for (int j = 0; j < 25; ++j) { acc0[j] = 0.f; acc1[j] = 0.f; }
    for (int kb = 0; kb < 200; kb += 8) {
        __syncthreads();
        if (tid < 128) {
            int row = tid >> 1, kp = (tid & 1) * 4;
            *(float4*)&Al[row][kp] = *(const float4*)&X[(size_t)(m0 + row) * V_ + k0 + kb + kp];
        }
        for (int i = tid; i < 400; i += 256) {
            int h = i >> 1, kp = (i & 1) * 4;
            *(float4*)&Bl[h][kp] = *(const float4*)&W[(size_t)h * V_ + k0 + kb + kp];
        }
        __syncthreads();
#pragma unroll
        for (int kc = 0; kc < 8; kc += 4) {
            float4 a0 = *(const float4*)&Al[r][kc];
            float4 a1 = *(const float4*)&Al[r + 32][kc];
#pragma unroll
            for (int j = 0; j < 25; ++j) {
                float4 bb = *(const float4*)&Bl[c * 25 + j][kc];
                acc0[j] += a0.x * bb.x + a0.y * bb.y + a0.z * bb.z + a0.w * bb.w;
                acc1[j] += a1.x * bb.x + a1.y * bb.y + a1.z * bb.z + a1.w * bb.w;
            }
        }
    }
    if (ATOMIC) {
#pragma unroll
        for (int j = 0; j < 25; ++j) {
            atomicAdd(&e1p[(size_t)(m0 + r) * H_ + c * 25 + j], acc0[j]);
            atomicAdd(&e1p[(size_t)(m0 + r + 32) * H_ + c * 25 + j], acc1[j]);
        }
    } else {
        float* out = e1p + (size_t)blockIdx.y * ((size_t)B_ * H_);
#pragma unroll
        for (int j = 0; j < 25; ++j) {
            out[(size_t)(m0 + r) * H_ + c * 25 + j] = acc0[j];
            out[(size_t)(m0 + r + 32) * H_ + c * 25 + j] = acc1[j];
        }
    }
}

// ---------------- encoder tail: slab-reduce -> softplus -> layer2 -> layer3 linear ----------------
__global__ __launch_bounds__(256) void k_enc_tail(const float* __restrict__ e1p,
                                                  int nslab,
                                                  const float* __restrict__ b11,
                                                  const float* __restrict__ W12,
                                                  const float* __restrict__ b12,
                                                  const float* __restrict__ W21,
                                                  const float* __restrict__ b21,
                                                  float* __restrict__ thetalin) {
    __shared__ float arow[H_];
    __shared__ float brow[H_];
    __shared__ float Wl[H_ * T_];   // 10000 floats, reused
    const int b = blockIdx.x, tid = threadIdx.x;
    if (tid < H_) {
        float v = b11[tid];
        for (int p = 0; p < nslab; ++p)
            v += e1p[(size_t)p * ((size_t)B_ * H_) + (size_t)b * H_ + tid];
        arow[tid] = sp_(v);
    }
    float acc = (tid < H_) ? b12[tid] : 0.f;
    for (int kc = 0; kc < 4; ++kc) {
        __syncthreads();
        for (int i = tid; i < H_ * T_; i += 256) {
            int h = i / T_, k = i % T_;
            Wl[i] = W12[h * H_ + kc * T_ + k];      // Wl layout [h][50]
        }
        __syncthreads();
        if (tid < H_) {
#pragma unroll 10
            for (int k = 0; k < T_; ++k) acc += arow[kc * T_ + k] * Wl[tid * T_ + k];
        }
    }
    __syncthreads();
    if (tid < H_) brow[tid] = sp_(acc);
    __syncthreads();
    for (int i = tid; i < T_ * H_; i += 256) Wl[i] = W21[i];  // [t][200]
    __syncthreads();
    if (tid < T_) {
        float a2 = b21[tid];
        for (int h = 0; h < H_; ++h) a2 += brow[h] * Wl[tid * H_ + h];
        thetalin[b * T_ + tid] = a2;
    }
}

// ---------------- BN stats over batch for theta (parallel: one block per topic) ----------------
__global__ __launch_bounds__(64) void k_bnstats(const float* __restrict__ thetalin,
                                                const float* __restrict__ g,
                                                const float* __restrict__ be,
                                                float* scale, float* shift) {
    const int t = blockIdx.x;       // 0..49
    const int lane = threadIdx.x;
    double s = 0.0, s2 = 0.0;
    for (int b = lane; b < B_; b += 64) {
        float x = thetalin[b * T_ + t];
        s += x; s2 += (double)x * x;
    }
#pragma unroll
    for (int off = 32; off; off >>= 1) {
        s  += __shfl_xor(s, off);
        s2 += __shfl_xor(s2, off);
    }
    if (lane == 0) {
        double mean = s / B_;
        float var = (float)(s2 / B_ - mean * mean);
        float sc = g[t] / sqrtf(var + EPS_);
        scale[t] = sc;
        shift[t] = be[t] - (float)mean * sc;
    }
}

// ---------------- softmax(theta), argmax -> enc_idx, counts, quant_loss ----------------
__global__ __launch_bounds__(64) void k_st(const float* __restrict__ thetalin,
                                           const float* __restrict__ scale,
                                           const float* __restrict__ shift,
                                           float* __restrict__ st, float* __restrict__ stnorm,
                                           int* __restrict__ enc_idx, int* __restrict__ cnt,
                                           float* __restrict__ buckets) {
    const int b = blockIdx.x, t = threadIdx.x;
    float x = (t < T_) ? thetalin[b * T_ + t] * scale[t] + shift[t] : -INFINITY;
    float m = x;
#pragma unroll
    for (int off = 32; off; off >>= 1) m = fmaxf(m, __shfl_xor(m, off));
    float e = (t < T_) ? expf(x - m) : 0.f;
    float ssum = e;
#pragma unroll
    for (int off = 32; off; off >>= 1) ssum += __shfl_xor(ssum, off);
    float stv = e / ssum;
    if (t < T_) st[b * T_ + t] = stv;
    float sn = stv * stv;
#pragma unroll
    for (int off = 32; off; off >>= 1) sn += __shfl_xor(sn, off);
    // argmax of x, first index wins ties  (== argmin of VQ distance)
    float bv = x; int bi = (t < T_) ? t : (1 << 30);
#pragma unroll
    for (int off = 32; off; off >>= 1) {
        float ov = __shfl_xor(bv, off); int oi = __shfl_xor(bi, off);
        if (ov > bv || (ov == bv && oi < bi)) { bv = ov; bi = oi; }
    }
    if (t == 0) {
        enc_idx[b] = bi;
        atomicAdd(&cnt[bi], 1);
        stnorm[b] = sn;
        float stmax = 1.f / ssum;  // st at argmax
        atomicAdd(&buckets[b], (1.25f / (float)(B_ * T_)) * (sn + 1.f - 2.f * stmax));
    }
}

// ---------------- decoder BN -> A[t][v] rows + k-major repack Ak[(v>>2)*200 + t*4 + (v&3)] ----------------
__global__ __launch_bounds__(256) void k_amat(const float* __restrict__ Wd,
                                              const int* __restrict__ cnt,
                                              const float* __restrict__ gd,
                                              const float* __restrict__ bd,
                                              float* __restrict__ A,
                                              float* __restrict__ Ak) {
    __shared__ float cl[T_];
    const int tid = threadIdx.x;
    if (tid < T_) cl[tid] = (float)cnt[tid];
    __syncthreads();
    int v = blockIdx.x * 256 + tid;
    if (v >= V_) return;
    float mean = 0.f, ex2 = 0.f;
#pragma unroll
    for (int t = 0; t < T_; ++t) {
        float w = Wd[v * T_ + t];
        mean += cl[t] * w; ex2 += cl[t] * w * w;
    }
    mean *= (1.f / B_); ex2 *= (1.f / B_);
    float rstd = 1.f / sqrtf(ex2 - mean * mean + EPS_);
    float g = gd[v], bb = bd[v];
    const int vq = v >> 2, vr = v & 3;
#pragma unroll
    for (int t = 0; t < T_; ++t) {
        float val = (Wd[v * T_ + t] - mean) * rstd * g + bb;
        A[(size_t)t * V_ + v] = val;
        if (Ak) Ak[(size_t)vq * 200 + t * 4 + vr] = val;
    }
}

// ---------------- lse[t] = logsumexp_v A[t][v] ----------------
__global__ __launch_bounds__(256) void k_lse(const float* __restrict__ A, float* __restrict__ lse) {
    __shared__ float red[4];
    const int t = blockIdx.x, tid = threadIdx.x;
    const float* row = A + (size_t)t * V_;
    float m = -INFINITY;
    for (int i = tid; i < V_; i += 256) m = fmaxf(m, row[i]);
#pragma unroll
    for (int off = 32; off; off >>= 1) m = fmaxf(m, __shfl_xor(m, off));
    if ((tid & 63) == 0) red[tid >> 6] = m;
    __syncthreads();
    m = fmaxf(fmaxf(red[0], red[1]), fmaxf(red[2], red[3]));
    float s = 0.f;
    for (int i = tid; i < V_; i += 256) s += expf(row[i] - m);
#pragma unroll
    for (int off = 32; off; off >>= 1) s += __shfl_xor(s, off);
    __syncthreads();
    if ((tid & 63) == 0) red[tid >> 6] = s;
    __syncthreads();
    if (tid == 0) lse[t] = m + logf(red[0] + red[1] + red[2] + red[3]);
}

// ---------------- fused cost + fuse + per-half top-20 ----------------
// grid 512: blockIdx = (rowblk<<1)|half ; 4 rows/block, one wave per row, 5000 n per half
__global__ __launch_bounds__(256) void k_fuse_topk(const float* __restrict__ st,
                                                   const float* __restrict__ stnorm,
                                                   const float* __restrict__ tb,
                                                   const float* __restrict__ tbn,
                                                   const float* __restrict__ Mcos,
                                                   const float* __restrict__ Mcoo,
                                                   const int* __restrict__ idx,
                                                   float* __restrict__ cand_v,
                                                   int* __restrict__ cand_i) {
    __shared__ __align__(16) float tbl[256 * T_];
    const int tid = threadIdx.x;
    const int lane = tid & 63, wv = tid >> 6;
    const int half = blockIdx.x & 1;
    const int r = (blockIdx.x >> 1) * 4 + wv;
    const int n0 = half * 5000;
    float sreg[T_];
#pragma unroll
    for (int k = 0; k < T_; ++k) sreg[k] = st[r * T_ + k];
    const float snr = stnorm[r];
    const int myidx = idx[r];
    const float* mcr = Mcos + (size_t)myidx * N_;
    const float* mor = Mcoo + (size_t)myidx * N_;
    float tv[K_]; int ti[K_];
#pragma unroll
    for (int s = 0; s < K_; ++s) { tv[s] = INFINITY; ti[s] = -1; }
    float worst = INFINITY;
    for (int c0 = 0; c0 < 5000; c0 += 256) {
        int nrows = min(256, 5000 - c0);
        __syncthreads();
        {
            const float4* src = (const float4*)(tb + (size_t)(n0 + c0) * T_);
            float4* dst = (float4*)tbl;
            int cnt4 = nrows * T_ / 4;
            for (int i = tid; i < cnt4; i += 256) dst[i] = src[i];
        }
        __syncthreads();
#pragma unroll
        for (int jj = 0; jj < 4; ++jj) {
            int nn = lane + 64 * jj;
            int n = n0 + c0 + nn;
            if (nn < nrows && n != myidx) {
                const float2* t2 = (const float2*)(tbl + nn * T_);
                float d = 0.f;
#pragma unroll
                for (int k = 0; k < T_ / 2; ++k) {
                    float2 w = t2[k];
                    d += sreg[2 * k] * w.x + sreg[2 * k + 1] * w.y;
                }
                float cost = snr + tbn[n] - 2.f * d;
                float f = 0.5f * cost * cost + 0.5f * (0.5f * mcr[n] + 0.5f * mor[n]);
                if (f < worst) {
                    bool done = false;
#pragma unroll
                    for (int s = 0; s < K_; ++s) {
                        bool mm = (!done) && (tv[s] == worst);
                        if (mm) { tv[s] = f; ti[s] = n; done = true; }
                    }
                    worst = tv[0];
#pragma unroll
                    for (int s = 1; s < K_; ++s) worst = fmaxf(worst, tv[s]);
                }
            }
        }
    }
    // wave-level merge: extract the 20 smallest across the 64 lane lists
    for (int it = 0; it < K_; ++it) {
        float mv = INFINITY; int mi = -1, ms = -1;
#pragma unroll
        for (int s = 0; s < K_; ++s) {
            bool better = tv[s] < mv;
            mv = better ? tv[s] : mv;
            mi = better ? ti[s] : mi;
            ms = better ? s : ms;
        }
        float bv = mv; int bn = mi, bl = lane, bs = ms;
#pragma unroll
        for (int off = 32; off; off >>= 1) {
            float ov = __shfl_xor(bv, off); int on = __shfl_xor(bn, off);
            int ol = __shfl_xor(bl, off);   int os = __shfl_xor(bs, off);
            if (ov < bv || (ov == bv && on < bn)) { bv = ov; bn = on; bl = ol; bs = os; }
        }
        if (lane == 0) {
            cand_v[(r * 2 + half) * K_ + it] = bv;
            cand_i[(r * 2 + half) * K_ + it] = bn;
        }
        if (lane == bl) {
#pragma unroll
            for (int s = 0; s < K_; ++s)
                if (s == bs) tv[s] = INFINITY;
        }
    }
}

// ---------------- merge the two per-half top-20 lists into final top-20 ----------------
__global__ __launch_bounds__(64) void k_merge40(const float* __restrict__ cand_v,
                                                const int* __restrict__ cand_i,
                                                int* __restrict__ topk) {
    const int b = blockIdx.x, lane = threadIdx.x;
    float v = (lane < 2 * K_) ? cand_v[b * 2 * K_ + lane] : INFINITY;
    int id = (lane < 2 * K_) ? cand_i[b * 2 * K_ + lane] : -1;
    for (int it = 0; it < K_; ++it) {
        float bv = v; int bn = id, bl = lane;
#pragma unroll
        for (int off = 32; off; off >>= 1) {
            float ov = __shfl_xor(bv, off); int on = __shfl_xor(bn, off);
            int ol = __shfl_xor(bl, off);
            if (ov < bv || (ov == bv && on < bn)) { bv = ov; bn = on; bl = ol; }
        }
        if (lane == 0) topk[b * K_ + it] = bn;
        if (lane == bl) v = INFINITY;
    }
}

// ---------------- P/Q GEMM: P[n][t] = dot(td[n], A[t]), col 50 = rowsum; same for inputs->Q ----------------
// grid (157+16, KSPLIT): lane owns one row; 4 waves split the block's k-range; LDS reduce; slab store.
__global__ __launch_bounds__(256) void k_pmat(const float* __restrict__ td,
                                              const float* __restrict__ inputs,
                                              const float* __restrict__ Ak,
                                              float* __restrict__ P,
                                              float* __restrict__ Q) {
    __shared__ float red[4][64][51];
    const int tid = threadIdx.x;
    const int m = tid & 63, w = tid >> 6;
    const int bx = blockIdx.x, ks = blockIdx.y;
    const float* src; float* out; int n0, maxr;
    if (bx < 157) { src = td;     out = P + (size_t)ks * PROWS_ * 51; n0 = bx * 64;        maxr = N_; }
    else          { src = inputs; out = Q + (size_t)ks * B_ * 51;     n0 = (bx - 157) * 64; maxr = B_; }
    const int n = n0 + m;
    const int base = 250 * ks;                      // f4 index base (1250 f4 per row total)
    const int lo = base + ((250 * w) >> 2);
    const int hi = base + ((250 * (w + 1)) >> 2);
    float acc[T_];
#pragma unroll
    for (int t = 0; t < T_; ++t) acc[t] = 0.f;
    float srow = 0.f;
    if (n < maxr) {
        const float4* row4 = (const float4*)(src + (size_t)n * V_);
        const float4* Ak4 = (const float4*)Ak;
        for (int k4 = lo; k4 < hi; ++k4) {
            float4 a = row4[k4];
            srow += a.x + a.y + a.z + a.w;
            const float4* ab = Ak4 + (size_t)k4 * 50;   // 50 lane-uniform f4 loads, imm offsets
#pragma unroll
            for (int t = 0; t < T_; ++t) {
                float4 wv = ab[t];
                acc[t] += a.x * wv.x + a.y * wv.y + a.z * wv.z + a.w * wv.w;
            }
        }
    }
#pragma unroll
    for (int t = 0; t < T_; ++t) red[w][m][t] = acc[t];   // stride 51: conflict-free
    red[w][m][50] = srow;
    __syncthreads();
    for (int i = tid; i < 64 * 51; i += 256) {
        float v = red[0][0][i] + red[1][0][i] + red[2][0][i] + red[3][0][i];
        out[(size_t)n0 * 51 + i] = v;                     // linear in i: coalesced
    }
}

// ---------------- rec loss assembly from P/Q lookups ----------------
__global__ __launch_bounds__(256) void k_rec2(const float* __restrict__ Q,
                                              const float* __restrict__ P,
                                              const float* __restrict__ lse,
                                              const int* __restrict__ topk,
                                              const int* __restrict__ enc_idx,
                                              const int* __restrict__ flag,
                                              float* __restrict__ buckets) {
    const int b = blockIdx.x * 256 + threadIdx.x;
    if (b >= B_) return;
    const int t = enc_idx[b];
    float q = 0.f, sx = 0.f;
#pragma unroll
    for (int ks = 0; ks < KSPLIT; ++ks) {
        const float* Qr = Q + ((size_t)ks * B_ + b) * 51;
        q += Qr[t]; sx += Qr[50];
    }
    float ps = 0.f, rs = 0.f;
    if (flag[0] != 0) {
        for (int k = 0; k < K_; ++k) {
            const int j = topk[b * K_ + k];
#pragma unroll
            for (int ks = 0; ks < KSPLIT; ++ks) {
                const float* Pr = P + ((size_t)ks * PROWS_ + j) * 51;
                ps += Pr[t]; rs += Pr[50];
            }
        }
    }
    const float xdot = q + 0.05f * ps;      // ALPHA/K = 1/20
    const float xsum = sx + 0.05f * rs;
    buckets[b] += (lse[t] * xsum - xdot) * (1.f / (float)B_);   // sole writer at this point
}

// ---------------- fallback (small ws): merged gather rec_loss ----------------
__global__ __launch_bounds__(256) void k_rec(const float* __restrict__ inputs,
                                             const float* __restrict__ td,
                                             const float* __restrict__ A,
                                             const float* __restrict__ lse,
                                             const int* __restrict__ topk,
                                             const int* __restrict__ enc_idx,
                                             const int* __restrict__ flag,
                                             float* __restrict__ buckets) {
    __shared__ float red[8];
    const int b = blockIdx.x, tid = threadIdx.x;
    const int t = enc_idx[b];
    float4 acc[5];
    const float4* xr = (const float4*)(inputs + (size_t)b * V_);
#pragma unroll
    for (int s = 0; s < 5; ++s) {
        int i = tid + 256 * s;
        acc[s] = (i < 1250) ? xr[i] : make_float4(0.f, 0.f, 0.f, 0.f);
    }
    if (flag[0] != 0) {
        float4 aug[5];
#pragma unroll
        for (int s = 0; s < 5; ++s) aug[s] = make_float4(0.f, 0.f, 0.f, 0.f);
        for (int k = 0; k < K_; ++k) {
            const float4* trow = (const float4*)(td + (size_t)topk[b * K_ + k] * V_);
#pragma unroll
            for (int s = 0; s < 5; ++s) {
                int i = tid + 256 * s;
                if (i < 1250) {
                    float4 v = trow[i];
                    aug[s].x += v.x; aug[s].y += v.y; aug[s].z += v.z; aug[s].w += v.w;
                }
            }
        }
#pragma unroll
        for (int s = 0; s < 5; ++s) {
            acc[s].x += 0.05f * aug[s].x;
            acc[s].y += 0.05f * aug[s].y;
            acc[s].z += 0.05f * aug[s].z;
            acc[s].w += 0.05f * aug[s].w;
        }
    }
    const float4* ar = (const float4*)(A + (size_t)t * V_);
    float dot = 0.f, ssum = 0.f;
#pragma unroll
    for (int s = 0; s < 5; ++s) {
        int i = tid + 256 * s;
        if (i < 1250) {
            float4 a = ar[i];
            dot += acc[s].x * a.x + acc[s].y * a.y + acc[s].z * a.z + acc[s].w * a.w;
            ssum += acc[s].x + acc[s].y + acc[s].z + acc[s].w;
        }
    }
#pragma unroll
    for (int off = 32; off; off >>= 1) {
        dot += __shfl_xor(dot, off);
        ssum += __shfl_xor(ssum, off);
    }
    if ((tid & 63) == 0) { red[(tid >> 6) * 2] = dot; red[(tid >> 6) * 2 + 1] = ssum; }
    __syncthreads();
    if (tid == 0) {
        float D = red[0] + red[2] + red[4] + red[6];
        float S = red[1] + red[3] + red[5] + red[7];
        atomicAdd(&buckets[b], (lse[t] * S - D) * (1.f / (float)B_));
    }
}

// ---------------- final reduce ----------------
__global__ __launch_bounds__(256) void k_final(const float* __restrict__ buckets, float* __restrict__ out) {
    __shared__ float red[4];
    const int tid = threadIdx.x;
    float v = buckets[tid] + buckets[tid + 256] + buckets[tid + 512] + buckets[tid + 768];
#pragma unroll
    for (int off = 32; off; off >>= 1) v += __shfl_xor(v, off);
    if ((tid & 63) == 0) red[tid >> 6] = v;
    __syncthreads();
    if (tid == 0) out[0] = red[0] + red[1] + red[2] + red[3];
}

extern "C" void kernel_launch(void* const* d_in, const int* in_sizes, int n_in,
                              void* d_out, int out_size, void* d_ws, size_t ws_size,
                              hipStream_t stream) {
    const int*   idx    = (const int*)d_in[0];
    const float* inputs = (const float*)d_in[1];
    const int*   flag   = (const int*)d_in[2];
    const float* td     = (const float*)d_in[3];
    const float* Mcos   = (const float*)d_in[4];
    const float* Mcoo   = (const float*)d_in[5];
    const float* tb     = (const float*)d_in[6];
    const float* W11    = (const float*)d_in[7];
    const float* b11    = (const float*)d_in[8];
    const float* W12    = (const float*)d_in[9];
    const float* b12    = (const float*)d_in[10];
    const float* W21    = (const float*)d_in[11];
    const float* b21    = (const float*)d_in[12];
    const float* gm     = (const float*)d_in[13];
    const float* bm     = (const float*)d_in[14];
    const float* gd     = (const float*)d_in[15];
    const float* bd     = (const float*)d_in[16];
    const float* Wd     = (const float*)d_in[17];
    float* out = (float*)d_out;

    const size_t slab  = (size_t)B_ * H_;            // 204800
    const size_t restw = 468128;                     // thetalin..topk incl Amat
    const size_t akw   = 250000;
    const size_t pw    = (size_t)KSPLIT * PROWS_ * 51;  // 2,562,240
    const size_t qw    = (size_t)KSPLIT * B_ * 51;      //   261,120
    const size_t szA = (NSLAB * slab + restw + akw + pw + qw) * 4;
    const size_t szB = (slab + restw + akw + pw + qw) * 4;
    const bool slab25 = (ws_size >= szA);
    const bool useP   = (ws_size >= szB) || slab25;
    const int  nslab  = slab25 ? NSLAB : 1;

    float* p        = (float*)d_ws;
    float* e1p      = p;            p += (size_t)nslab * slab;
    float* thetalin = p;            p += 51200;
    float* st       = p;            p += 51200;
    float* stnorm   = p;            p += 1024;
    float* scale    = p;            p += 64;
    float* shift    = p;            p += 64;
    float* Amat     = p;            p += 250000;
    float* lse      = p;            p += 64;
    float* tbn      = p;            p += 10000;
    float* buckets  = p;            p += 1024;
    float* cand_v   = p;            p += 40960;
    int*   enc_idx  = (int*)p;      p += 1024;
    int*   cnt      = (int*)p;      p += 64;
    int*   cand_i   = (int*)p;      p += 40960;
    int*   topk     = (int*)p;      p += 20480;
    float* Ak       = useP ? p : nullptr;   p += useP ? akw : 0;
    float* P        = useP ? p : nullptr;   p += useP ? pw : 0;
    float* Q        = useP ? p : nullptr;

    k_init<<<40, 256, 0, stream>>>(tb, tbn, buckets, cnt);
    if (slab25) {
        k_gemm1<false><<<dim3(16, 25), 256, 0, stream>>>(inputs, W11, e1p);
    } else {
        k_zero<<<800, 256, 0, stream>>>(e1p);
        k_gemm1<true><<<dim3(16, 25), 256, 0, stream>>>(inputs, W11, e1p);
    }
    k_enc_tail<<<1024, 256, 0, stream>>>(e1p, nslab, b11, W12, b12, W21, b21, thetalin);
    k_bnstats<<<50, 64, 0, stream>>>(thetalin, gm, bm, scale, shift);
    k_st<<<1024, 64, 0, stream>>>(thetalin, scale, shift, st, stnorm, enc_idx, cnt, buckets);
    k_amat<<<20, 256, 0, stream>>>(Wd, cnt, gd, bd, Amat, Ak);
    k_lse<<<50, 256, 0, stream>>>(Amat, lse);
    k_fuse_topk<<<512, 256, 0, stream>>>(st, stnorm, tb, tbn, Mcos, Mcoo, idx, cand_v, cand_i);
    k_merge40<<<1024, 64, 0, stream>>>(cand_v, cand_i, topk);
    if (useP) {
        k_pmat<<<dim3(157 + 16, KSPLIT), 256, 0, stream>>>(td, inputs, Ak, P, Q);
        k_rec2<<<4, 256, 0, stream>>>(Q, P, lse, topk, enc_idx, flag, buckets);
    } else {
        k_rec<<<1024, 256, 0, stream>>>(inputs, td, Amat, lse, topk, enc_idx, flag, buckets);
    }
    k_final<<<1, 256, 0, stream>>>(buckets, out);
}

// Round 3
// 1487.340 us; speedup vs baseline: 1.1689x; 1.1689x over previous
//
#include <hip/hip_runtime.h>
#include <math.h>

#define B_ 1024
#define V_ 5000
#define N_ 10000
#define T_ 50
#define H_ 200
#define K_ 20
#define EPS_ 1e-5f
#define NSLAB 25
#define RTOT_ 11024      // N + B combined rows
#define RPAD_ 11264      // 44 * 256
#define PST_ 52          // PQ row stride (50 dots + rowsum + pad)

__device__ __forceinline__ float sp_(float x) {
    return (x > 20.f) ? x : log1pf(expf(x));
}

// ---------------- init: zero buckets + cnt, compute tbn[n] = ||theta_bank[n]||^2 ----------------
__global__ __launch_bounds__(256) void k_init(const float* __restrict__ tb,
                                              float* __restrict__ tbn,
                                              float* buckets, int* cnt) {
    int i = blockIdx.x * 256 + threadIdx.x;
    if (blockIdx.x == 0) {
        int t = threadIdx.x;
#pragma unroll
        for (int s = 0; s < 4; ++s) buckets[t + 256 * s] = 0.f;
        if (t < 64) cnt[t] = 0;
    }
    if (i < N_) {
        const float* r = tb + (size_t)i * T_;
        float s = 0.f;
#pragma unroll
        for (int t = 0; t < T_; ++t) { float x = r[t]; s += x * x; }
        tbn[i] = s;
    }
}

// fallback-only: zero e1a when using the atomic path
__global__ __launch_bounds__(256) void k_zero(float* p) {
    int i = blockIdx.x * 256 + threadIdx.x;
    if (i < B_ * H_) p[i] = 0.f;
}

// ---------------- GEMM1: e1 partials = inputs @ W11^T  (k-split, 25 slabs or atomics) ----------------
template <bool ATOMIC>
__global__ __launch_bounds__(256) void k_gemm1(const float* __restrict__ X,
                                               const float* __restrict__ W,
                                               float* __restrict__ e1p) {
    __shared__ __align__(16) float Al[64][12];
    __shared__ __align__(16) float Bl[200][8];
    const int tid = threadIdx.x;
    const int r = tid & 31, c = tid >> 5;
    const int m0 = blockIdx.x * 64;
    const int k0 = blockIdx.y * 200;
    float acc0[25], acc1[25];
#pragma unroll
    for (int j = 0; j < 25; ++j) { acc0[j] = 0.f; acc1[j] = 0.f; }
    for (int kb = 0; kb < 200; kb += 8) {
        __syncthreads();
        if (tid < 128) {
            int row = tid >> 1, kp = (tid & 1) * 4;
            *(float4*)&Al[row][kp] = *(const float4*)&X[(size_t)(m0 + row) * V_ + k0 + kb + kp];
        }
        for (int i = tid; i < 400; i += 256) {
            int h = i >> 1, kp = (i & 1) * 4;
            *(float4*)&Bl[h][kp] = *(const float4*)&W[(size_t)h * V_ + k0 + kb + kp];
        }
        __syncthreads();
#pragma unroll
        for (int kc = 0; kc < 8; kc += 4) {
            float4 a0 = *(const float4*)&Al[r][kc];
            float4 a1 = *(const float4*)&Al[r + 32][kc];
#pragma unroll
            for (int j = 0; j < 25; ++j) {
                float4 bb = *(const float4*)&Bl[c * 25 + j][kc];
                acc0[j] += a0.x * bb.x + a0.y * bb.y + a0.z * bb.z + a0.w * bb.w;
                acc1[j] += a1.x * bb.x + a1.y * bb.y + a1.z * bb.z + a1.w * bb.w;
            }
        }
    }
    if (ATOMIC) {
#pragma unroll
        for (int j = 0; j < 25; ++j) {
            atomicAdd(&e1p[(size_t)(m0 + r) * H_ + c * 25 + j], acc0[j]);
            atomicAdd(&e1p[(size_t)(m0 + r + 32) * H_ + c * 25 + j], acc1[j]);
        }
    } else {
        float* out = e1p + (size_t)blockIdx.y * ((size_t)B_ * H_);
#pragma unroll
        for (int j = 0; j < 25; ++j) {
            out[(size_t)(m0 + r) * H_ + c * 25 + j] = acc0[j];
            out[(size_t)(m0 + r + 32) * H_ + c * 25 + j] = acc1[j];
        }
    }
}

// ---------------- encoder tail ----------------
__global__ __launch_bounds__(256) void k_enc_tail(const float* __restrict__ e1p,
                                                  int nslab,
                                                  const float* __restrict__ b11,
                                                  const float* __restrict__ W12,
                                                  const float* __restrict__ b12,
                                                  const float* __restrict__ W21,
                                                  const float* __restrict__ b21,
                                                  float* __restrict__ thetalin) {
    __shared__ float arow[H_];
    __shared__ float brow[H_];
    __shared__ float Wl[H_ * T_];
    const int b = blockIdx.x, tid = threadIdx.x;
    if (tid < H_) {
        float v = b11[tid];
        for (int p = 0; p < nslab; ++p)
            v += e1p[(size_t)p * ((size_t)B_ * H_) + (size_t)b * H_ + tid];
        arow[tid] = sp_(v);
    }
    float acc = (tid < H_) ? b12[tid] : 0.f;
    for (int kc = 0; kc < 4; ++kc) {
        __syncthreads();
        for (int i = tid; i < H_ * T_; i += 256) {
            int h = i / T_, k = i % T_;
            Wl[i] = W12[h * H_ + kc * T_ + k];
        }
        __syncthreads();
        if (tid < H_) {
#pragma unroll 10
            for (int k = 0; k < T_; ++k) acc += arow[kc * T_ + k] * Wl[tid * T_ + k];
        }
    }
    __syncthreads();
    if (tid < H_) brow[tid] = sp_(acc);
    __syncthreads();
    for (int i = tid; i < T_ * H_; i += 256) Wl[i] = W21[i];
    __syncthreads();
    if (tid < T_) {
        float a2 = b21[tid];
        for (int h = 0; h < H_; ++h) a2 += brow[h] * Wl[tid * H_ + h];
        thetalin[b * T_ + tid] = a2;
    }
}

// ---------------- BN stats over batch for theta ----------------
__global__ __launch_bounds__(64) void k_bnstats(const float* __restrict__ thetalin,
                                                const float* __restrict__ g,
                                                const float* __restrict__ be,
                                                float* scale, float* shift) {
    const int t = blockIdx.x;
    const int lane = threadIdx.x;
    double s = 0.0, s2 = 0.0;
    for (int b = lane; b < B_; b += 64) {
        float x = thetalin[b * T_ + t];
        s += x; s2 += (double)x * x;
    }
#pragma unroll
    for (int off = 32; off; off >>= 1) {
        s  += __shfl_xor(s, off);
        s2 += __shfl_xor(s2, off);
    }
    if (lane == 0) {
        double mean = s / B_;
        float var = (float)(s2 / B_ - mean * mean);
        float sc = g[t] / sqrtf(var + EPS_);
        scale[t] = sc;
        shift[t] = be[t] - (float)mean * sc;
    }
}

// ---------------- softmax(theta), argmax, quant_loss ----------------
__global__ __launch_bounds__(64) void k_st(const float* __restrict__ thetalin,
                                           const float* __restrict__ scale,
                                           const float* __restrict__ shift,
                                           float* __restrict__ st, float* __restrict__ stnorm,
                                           int* __restrict__ enc_idx, int* __restrict__ cnt,
                                           float* __restrict__ buckets) {
    const int b = blockIdx.x, t = threadIdx.x;
    float x = (t < T_) ? thetalin[b * T_ + t] * scale[t] + shift[t] : -INFINITY;
    float m = x;
#pragma unroll
    for (int off = 32; off; off >>= 1) m = fmaxf(m, __shfl_xor(m, off));
    float e = (t < T_) ? expf(x - m) : 0.f;
    float ssum = e;
#pragma unroll
    for (int off = 32; off; off >>= 1) ssum += __shfl_xor(ssum, off);
    float stv = e / ssum;
    if (t < T_) st[b * T_ + t] = stv;
    float sn = stv * stv;
#pragma unroll
    for (int off = 32; off; off >>= 1) sn += __shfl_xor(sn, off);
    float bv = x; int bi = (t < T_) ? t : (1 << 30);
#pragma unroll
    for (int off = 32; off; off >>= 1) {
        float ov = __shfl_xor(bv, off); int oi = __shfl_xor(bi, off);
        if (ov > bv || (ov == bv && oi < bi)) { bv = ov; bi = oi; }
    }
    if (t == 0) {
        enc_idx[b] = bi;
        atomicAdd(&cnt[bi], 1);
        stnorm[b] = sn;
        float stmax = 1.f / ssum;
        atomicAdd(&buckets[b], (1.25f / (float)(B_ * T_)) * (sn + 1.f - 2.f * stmax));
    }
}

// ---------------- decoder BN -> A[t][v] rows + padded repack Ak[v][64] (col50 = 1.0) ----------------
__global__ __launch_bounds__(256) void k_amat(const float* __restrict__ Wd,
                                              const int* __restrict__ cnt,
                                              const float* __restrict__ gd,
                                              const float* __restrict__ bd,
                                              float* __restrict__ A,
                                              float* __restrict__ Ak) {
    __shared__ float cl[T_];
    const int tid = threadIdx.x;
    if (tid < T_) cl[tid] = (float)cnt[tid];
    __syncthreads();
    int v = blockIdx.x * 256 + tid;
    if (v >= V_) return;
    float mean = 0.f, ex2 = 0.f;
#pragma unroll
    for (int t = 0; t < T_; ++t) {
        float w = Wd[v * T_ + t];
        mean += cl[t] * w; ex2 += cl[t] * w * w;
    }
    mean *= (1.f / B_); ex2 *= (1.f / B_);
    float rstd = 1.f / sqrtf(ex2 - mean * mean + EPS_);
    float g = gd[v], bb = bd[v];
#pragma unroll
    for (int t = 0; t < T_; ++t) {
        float val = (Wd[v * T_ + t] - mean) * rstd * g + bb;
        A[(size_t)t * V_ + v] = val;
        if (Ak) Ak[(size_t)v * 64 + t] = val;
    }
    if (Ak) {
        Ak[(size_t)v * 64 + 50] = 1.0f;   // rowsum falls out of the GEMM for free
#pragma unroll
        for (int t = 51; t < 64; ++t) Ak[(size_t)v * 64 + t] = 0.f;
    }
}

// ---------------- lse[t] = logsumexp_v A[t][v] ----------------
__global__ __launch_bounds__(256) void k_lse(const float* __restrict__ A, float* __restrict__ lse) {
    __shared__ float red[4];
    const int t = blockIdx.x, tid = threadIdx.x;
    const float* row = A + (size_t)t * V_;
    float m = -INFINITY;
    for (int i = tid; i < V_; i += 256) m = fmaxf(m, row[i]);
#pragma unroll
    for (int off = 32; off; off >>= 1) m = fmaxf(m, __shfl_xor(m, off));
    if ((tid & 63) == 0) red[tid >> 6] = m;
    __syncthreads();
    m = fmaxf(fmaxf(red[0], red[1]), fmaxf(red[2], red[3]));
    float s = 0.f;
    for (int i = tid; i < V_; i += 256) s += expf(row[i] - m);
#pragma unroll
    for (int off = 32; off; off >>= 1) s += __shfl_xor(s, off);
    __syncthreads();
    if ((tid & 63) == 0) red[tid >> 6] = s;
    __syncthreads();
    if (tid == 0) lse[t] = m + logf(red[0] + red[1] + red[2] + red[3]);
}

// ---------------- fused cost + fuse + per-half top-20 ----------------
__global__ __launch_bounds__(256) void k_fuse_topk(const float* __restrict__ st,
                                                   const float* __restrict__ stnorm,
                                                   const float* __restrict__ tb,
                                                   const float* __restrict__ tbn,
                                                   const float* __restrict__ Mcos,
                                                   const float* __restrict__ Mcoo,
                                                   const int* __restrict__ idx,
                                                   float* __restrict__ cand_v,
                                                   int* __restrict__ cand_i) {
    __shared__ __align__(16) float tbl[256 * T_];
    const int tid = threadIdx.x;
    const int lane = tid & 63, wv = tid >> 6;
    const int half = blockIdx.x & 1;
    const int r = (blockIdx.x >> 1) * 4 + wv;
    const int n0 = half * 5000;
    float sreg[T_];
#pragma unroll
    for (int k = 0; k < T_; ++k) sreg[k] = st[r * T_ + k];
    const float snr = stnorm[r];
    const int myidx = idx[r];
    const float* mcr = Mcos + (size_t)myidx * N_;
    const float* mor = Mcoo + (size_t)myidx * N_;
    float tv[K_]; int ti[K_];
#pragma unroll
    for (int s = 0; s < K_; ++s) { tv[s] = INFINITY; ti[s] = -1; }
    float worst = INFINITY;
    for (int c0 = 0; c0 < 5000; c0 += 256) {
        int nrows = min(256, 5000 - c0);
        __syncthreads();
        {
            const float4* src = (const float4*)(tb + (size_t)(n0 + c0) * T_);
            float4* dst = (float4*)tbl;
            int cnt4 = nrows * T_ / 4;
            for (int i = tid; i < cnt4; i += 256) dst[i] = src[i];
        }
        __syncthreads();
#pragma unroll
        for (int jj = 0; jj < 4; ++jj) {
            int nn = lane + 64 * jj;
            int n = n0 + c0 + nn;
            if (nn < nrows && n != myidx) {
                const float2* t2 = (const float2*)(tbl + nn * T_);
                float d = 0.f;
#pragma unroll
                for (int k = 0; k < T_ / 2; ++k) {
                    float2 w = t2[k];
                    d += sreg[2 * k] * w.x + sreg[2 * k + 1] * w.y;
                }
                float cost = snr + tbn[n] - 2.f * d;
                float f = 0.5f * cost * cost + 0.5f * (0.5f * mcr[n] + 0.5f * mor[n]);
                if (f < worst) {
                    bool done = false;
#pragma unroll
                    for (int s = 0; s < K_; ++s) {
                        bool mm = (!done) && (tv[s] == worst);
                        if (mm) { tv[s] = f; ti[s] = n; done = true; }
                    }
                    worst = tv[0];
#pragma unroll
                    for (int s = 1; s < K_; ++s) worst = fmaxf(worst, tv[s]);
                }
            }
        }
    }
    for (int it = 0; it < K_; ++it) {
        float mv = INFINITY; int mi = -1, ms = -1;
#pragma unroll
        for (int s = 0; s < K_; ++s) {
            bool better = tv[s] < mv;
            mv = better ? tv[s] : mv;
            mi = better ? ti[s] : mi;
            ms = better ? s : ms;
        }
        float bv = mv; int bn = mi, bl = lane, bs = ms;
#pragma unroll
        for (int off = 32; off; off >>= 1) {
            float ov = __shfl_xor(bv, off); int on = __shfl_xor(bn, off);
            int ol = __shfl_xor(bl, off);   int os = __shfl_xor(bs, off);
            if (ov < bv || (ov == bv && on < bn)) { bv = ov; bn = on; bl = ol; bs = os; }
        }
        if (lane == 0) {
            cand_v[(r * 2 + half) * K_ + it] = bv;
            cand_i[(r * 2 + half) * K_ + it] = bn;
        }
        if (lane == bl) {
#pragma unroll
            for (int s = 0; s < K_; ++s)
                if (s == bs) tv[s] = INFINITY;
        }
    }
}

// ---------------- merge the two per-half top-20 lists ----------------
__global__ __launch_bounds__(64) void k_merge40(const float* __restrict__ cand_v,
                                                const int* __restrict__ cand_i,
                                                int* __restrict__ topk) {
    const int b = blockIdx.x, lane = threadIdx.x;
    float v = (lane < 2 * K_) ? cand_v[b * 2 * K_ + lane] : INFINITY;
    int id = (lane < 2 * K_) ? cand_i[b * 2 * K_ + lane] : -1;
    for (int it = 0; it < K_; ++it) {
        float bv = v; int bn = id, bl = lane;
#pragma unroll
        for (int off = 32; off; off >>= 1) {
            float ov = __shfl_xor(bv, off); int on = __shfl_xor(bn, off);
            int ol = __shfl_xor(bl, off);
            if (ov < bv || (ov == bv && on < bn)) { bv = ov; bn = on; bl = ol; }
        }
        if (lane == 0) topk[b * K_ + it] = bn;
        if (lane == bl) v = INFINITY;
    }
}

// ---------------- register-tiled fp32 GEMM: PQ[ks][row][0..49]=dot(row,A[t]), [50]=rowsum ----------------
// rows 0..9999 = td, 10000..11023 = inputs. grid (44, ksplits). block 128 thr = 2 waves.
// Each block: 256 rows x 64 cols; thread tile 8 rows x 16 cols; k staged in 20-float LDS chunks.
__global__ __launch_bounds__(128, 2) void k_pgemm(const float* __restrict__ td,
                                                  const float* __restrict__ inputs,
                                                  const float* __restrict__ Ak,
                                                  float* __restrict__ PQ,
                                                  int ksize) {
    __shared__ __align__(16) float Xl[256][28];   // 20 used + pad (28: 2-way bank spread)
    __shared__ __align__(16) float Al[20][64];
    const int tid = threadIdx.x;
    const int rg = tid >> 2;          // 0..31
    const int cg16 = (tid & 3) * 16;  // col base 0/16/32/48
    const int n0 = blockIdx.x * 256;
    const int ks = blockIdx.y;
    const int k0 = ks * ksize;
    float4 acc[8][4];
#pragma unroll
    for (int i = 0; i < 8; ++i)
#pragma unroll
        for (int j = 0; j < 4; ++j) acc[i][j] = make_float4(0.f, 0.f, 0.f, 0.f);

    for (int kb = k0; kb < k0 + ksize; kb += 20) {
        __syncthreads();
        // stage X: 256 rows x 5 f4
        for (int ii = tid; ii < 1280; ii += 128) {
            int row = ii / 5, p = (ii % 5) * 4;
            int gr = n0 + row;
            float4 vx = make_float4(0.f, 0.f, 0.f, 0.f);
            if (gr < RTOT_) {
                const float* src = (gr < N_) ? td + (size_t)gr * V_
                                             : inputs + (size_t)(gr - N_) * V_;
                vx = *(const float4*)&src[kb + p];
            }
            *(float4*)&Xl[row][p] = vx;
        }
        // stage A: 20 k x 16 f4
        for (int ii = tid; ii < 320; ii += 128) {
            int k = ii >> 4, c4 = (ii & 15) * 4;
            *(float4*)&Al[k][c4] = *(const float4*)&Ak[(size_t)(kb + k) * 64 + c4];
        }
        __syncthreads();
#pragma unroll
        for (int kk = 0; kk < 20; kk += 4) {
            float4 xv[8];
#pragma unroll
            for (int i = 0; i < 8; ++i) xv[i] = *(const float4*)&Xl[rg + 32 * i][kk];
#pragma unroll
            for (int k = 0; k < 4; ++k) {
                float4 a0 = *(const float4*)&Al[kk + k][cg16];
                float4 a1 = *(const float4*)&Al[kk + k][cg16 + 4];
                float4 a2 = *(const float4*)&Al[kk + k][cg16 + 8];
                float4 a3 = *(const float4*)&Al[kk + k][cg16 + 12];
#pragma unroll
                for (int i = 0; i < 8; ++i) {
                    float x = (k == 0) ? xv[i].x : (k == 1) ? xv[i].y
                            : (k == 2) ? xv[i].z : xv[i].w;
                    acc[i][0].x += x * a0.x; acc[i][0].y += x * a0.y;
                    acc[i][0].z += x * a0.z; acc[i][0].w += x * a0.w;
                    acc[i][1].x += x * a1.x; acc[i][1].y += x * a1.y;
                    acc[i][1].z += x * a1.z; acc[i][1].w += x * a1.w;
                    acc[i][2].x += x * a2.x; acc[i][2].y += x * a2.y;
                    acc[i][2].z += x * a2.z; acc[i][2].w += x * a2.w;
                    acc[i][3].x += x * a3.x; acc[i][3].y += x * a3.y;
                    acc[i][3].z += x * a3.z; acc[i][3].w += x * a3.w;
                }
            }
        }
    }
    // epilogue: cols 0..51 stored (cg 3 stores only its first f4 = cols 48..51)
#pragma unroll
    for (int i = 0; i < 8; ++i) {
        int row = n0 + rg + 32 * i;
        if (row < RTOT_) {
            float* dst = PQ + ((size_t)ks * RPAD_ + row) * PST_ + cg16;
            *(float4*)&dst[0] = acc[i][0];
            if (cg16 < 48) {
                *(float4*)&dst[4]  = acc[i][1];
                *(float4*)&dst[8]  = acc[i][2];
                *(float4*)&dst[12] = acc[i][3];
            }
        }
    }
}

// ---------------- rec loss assembly from PQ lookups (parallel over b x ks) ----------------
__global__ __launch_bounds__(256) void k_rec2(const float* __restrict__ PQ,
                                              const float* __restrict__ lse,
                                              const int* __restrict__ topk,
                                              const int* __restrict__ enc_idx,
                                              const int* __restrict__ flag,
                                              float* __restrict__ buckets,
                                              int ksplits) {
    const int gid = blockIdx.x * 256 + threadIdx.x;
    if (gid >= B_ * ksplits) return;
    const int b = gid / ksplits, ks = gid % ksplits;
    const int t = enc_idx[b];
    const float* Qr = PQ + ((size_t)ks * RPAD_ + N_ + b) * PST_;
    float q = Qr[t], sx = Qr[50];
    float ps = 0.f, rs = 0.f;
    if (flag[0] != 0) {
        for (int k = 0; k < K_; ++k) {
            const int j = topk[b * K_ + k];
            const float* Pr = PQ + ((size_t)ks * RPAD_ + j) * PST_;
            ps += Pr[t]; rs += Pr[50];
        }
    }
    const float val = (lse[t] * (sx + 0.05f * rs) - (q + 0.05f * ps)) * (1.f / (float)B_);
    atomicAdd(&buckets[b], val);
}

// ---------------- fallback (small ws): merged gather rec_loss ----------------
__global__ __launch_bounds__(256) void k_rec(const float* __restrict__ inputs,
                                             const float* __restrict__ td,
                                             const float* __restrict__ A,
                                             const float* __restrict__ lse,
                                             const int* __restrict__ topk,
                                             const int* __restrict__ enc_idx,
                                             const int* __restrict__ flag,
                                             float* __restrict__ buckets) {
    __shared__ float red[8];
    const int b = blockIdx.x, tid = threadIdx.x;
    const int t = enc_idx[b];
    float4 acc[5];
    const float4* xr = (const float4*)(inputs + (size_t)b * V_);
#pragma unroll
    for (int s = 0; s < 5; ++s) {
        int i = tid + 256 * s;
        acc[s] = (i < 1250) ? xr[i] : make_float4(0.f, 0.f, 0.f, 0.f);
    }
    if (flag[0] != 0) {
        float4 aug[5];
#pragma unroll
        for (int s = 0; s < 5; ++s) aug[s] = make_float4(0.f, 0.f, 0.f, 0.f);
        for (int k = 0; k < K_; ++k) {
            const float4* trow = (const float4*)(td + (size_t)topk[b * K_ + k] * V_);
#pragma unroll
            for (int s = 0; s < 5; ++s) {
                int i = tid + 256 * s;
                if (i < 1250) {
                    float4 v = trow[i];
                    aug[s].x += v.x; aug[s].y += v.y; aug[s].z += v.z; aug[s].w += v.w;
                }
            }
        }
#pragma unroll
        for (int s = 0; s < 5; ++s) {
            acc[s].x += 0.05f * aug[s].x;
            acc[s].y += 0.05f * aug[s].y;
            acc[s].z += 0.05f * aug[s].z;
            acc[s].w += 0.05f * aug[s].w;
        }
    }
    const float4* ar = (const float4*)(A + (size_t)t * V_);
    float dot = 0.f, ssum = 0.f;
#pragma unroll
    for (int s = 0; s < 5; ++s) {
        int i = tid + 256 * s;
        if (i < 1250) {
            float4 a = ar[i];
            dot += acc[s].x * a.x + acc[s].y * a.y + acc[s].z * a.z + acc[s].w * a.w;
            ssum += acc[s].x + acc[s].y + acc[s].z + acc[s].w;
        }
    }
#pragma unroll
    for (int off = 32; off; off >>= 1) {
        dot += __shfl_xor(dot, off);
        ssum += __shfl_xor(ssum, off);
    }
    if ((tid & 63) == 0) { red[(tid >> 6) * 2] = dot; red[(tid >> 6) * 2 + 1] = ssum; }
    __syncthreads();
    if (tid == 0) {
        float D = red[0] + red[2] + red[4] + red[6];
        float S = red[1] + red[3] + red[5] + red[7];
        atomicAdd(&buckets[b], (lse[t] * S - D) * (1.f / (float)B_));
    }
}

// ---------------- final reduce ----------------
__global__ __launch_bounds__(256) void k_final(const float* __restrict__ buckets, float* __restrict__ out) {
    __shared__ float red[4];
    const int tid = threadIdx.x;
    float v = buckets[tid] + buckets[tid + 256] + buckets[tid + 512] + buckets[tid + 768];
#pragma unroll
    for (int off = 32; off; off >>= 1) v += __shfl_xor(v, off);
    if ((tid & 63) == 0) red[tid >> 6] = v;
    __syncthreads();
    if (tid == 0) out[0] = red[0] + red[1] + red[2] + red[3];
}

extern "C" void kernel_launch(void* const* d_in, const int* in_sizes, int n_in,
                              void* d_out, int out_size, void* d_ws, size_t ws_size,
                              hipStream_t stream) {
    const int*   idx    = (const int*)d_in[0];
    const float* inputs = (const float*)d_in[1];
    const int*   flag   = (const int*)d_in[2];
    const float* td     = (const float*)d_in[3];
    const float* Mcos   = (const float*)d_in[4];
    const float* Mcoo   = (const float*)d_in[5];
    const float* tb     = (const float*)d_in[6];
    const float* W11    = (const float*)d_in[7];
    const float* b11    = (const float*)d_in[8];
    const float* W12    = (const float*)d_in[9];
    const float* b12    = (const float*)d_in[10];
    const float* W21    = (const float*)d_in[11];
    const float* b21    = (const float*)d_in[12];
    const float* gm     = (const float*)d_in[13];
    const float* bm     = (const float*)d_in[14];
    const float* gd     = (const float*)d_in[15];
    const float* bd     = (const float*)d_in[16];
    const float* Wd     = (const float*)d_in[17];
    float* out = (float*)d_out;

    const size_t slab  = (size_t)B_ * H_;      // 204800
    const size_t restw = 468128;               // thetalin..topk (incl Amat)
    const size_t akw   = 320000;               // Ak[5000][64]
    const size_t pqrow = (size_t)RPAD_ * PST_; // 585728 per split

    // tier selection: PQ aliases the dead e1p region (e1p dead after k_enc_tail)
    int ksplits = 0; int nslab = 1; bool useP = false;
    {
        struct { int ks; int ns; } tiers[] = {{25, NSLAB}, {10, NSLAB}, {5, NSLAB}, {5, 1}};
        for (auto& tr : tiers) {
            size_t uni = tr.ns * slab;
            size_t pq = (size_t)tr.ks * pqrow;
            if (pq > uni) uni = pq;
            if (ws_size >= (uni + restw + akw) * 4) {
                ksplits = tr.ks; nslab = tr.ns; useP = true; break;
            }
        }
        if (!useP) nslab = (ws_size >= (NSLAB * slab + restw) * 4) ? NSLAB : 1;
    }

    size_t uni_w = (size_t)nslab * slab;
    if (useP) { size_t pq = (size_t)ksplits * pqrow; if (pq > uni_w) uni_w = pq; }

    float* p        = (float*)d_ws;
    float* e1p      = p;
    float* PQ       = p;            p += uni_w;       // union region
    float* thetalin = p;            p += 51200;
    float* st       = p;            p += 51200;
    float* stnorm   = p;            p += 1024;
    float* scale    = p;            p += 64;
    float* shift    = p;            p += 64;
    float* Amat     = p;            p += 250000;
    float* lse      = p;            p += 64;
    float* tbn      = p;            p += 10000;
    float* buckets  = p;            p += 1024;
    float* cand_v   = p;            p += 40960;
    int*   enc_idx  = (int*)p;      p += 1024;
    int*   cnt      = (int*)p;      p += 64;
    int*   cand_i   = (int*)p;      p += 40960;
    int*   topk     = (int*)p;      p += 20480;
    float* Ak       = useP ? p : nullptr;

    k_init<<<40, 256, 0, stream>>>(tb, tbn, buckets, cnt);
    if (nslab == NSLAB) {
        k_gemm1<false><<<dim3(16, 25), 256, 0, stream>>>(inputs, W11, e1p);
    } else {
        k_zero<<<800, 256, 0, stream>>>(e1p);
        k_gemm1<true><<<dim3(16, 25), 256, 0, stream>>>(inputs, W11, e1p);
    }
    k_enc_tail<<<1024, 256, 0, stream>>>(e1p, nslab, b11, W12, b12, W21, b21, thetalin);
    k_bnstats<<<50, 64, 0, stream>>>(thetalin, gm, bm, scale, shift);
    k_st<<<1024, 64, 0, stream>>>(thetalin, scale, shift, st, stnorm, enc_idx, cnt, buckets);
    k_amat<<<20, 256, 0, stream>>>(Wd, cnt, gd, bd, Amat, Ak);
    k_lse<<<50, 256, 0, stream>>>(Amat, lse);
    k_fuse_topk<<<512, 256, 0, stream>>>(st, stnorm, tb, tbn, Mcos, Mcoo, idx, cand_v, cand_i);
    k_merge40<<<1024, 64, 0, stream>>>(cand_v, cand_i, topk);
    if (useP) {
        int ksize = 5000 / ksplits;
        k_pgemm<<<dim3(44, ksplits), 128, 0, stream>>>(td, inputs, Ak, PQ, ksize);
        int nrec = (B_ * ksplits + 255) / 256;
        k_rec2<<<nrec, 256, 0, stream>>>(PQ, lse, topk, enc_idx, flag, buckets, ksplits);
    } else {
        k_rec<<<1024, 256, 0, stream>>>(inputs, td, Amat, lse, topk, enc_idx, flag, buckets);
    }
    k_final<<<1, 256, 0, stream>>>(buckets, out);
}